// Round 12
// baseline (441.767 us; speedup 1.0000x reference)
//
#include <hip/hip_runtime.h>
#include <math.h>

#define NEG_SLOPE 0.2f

typedef _Float16 half8 __attribute__((ext_vector_type(8)));
typedef _Float16 half4 __attribute__((ext_vector_type(4)));
typedef _Float16 half2v __attribute__((ext_vector_type(2)));
typedef float    f32x4 __attribute__((ext_vector_type(4)));
typedef float    fvec4 __attribute__((ext_vector_type(4)));
typedef float    fvec2 __attribute__((ext_vector_type(2)));

typedef __attribute__((address_space(1))) const unsigned int gau32;
typedef __attribute__((address_space(3))) unsigned int lau32;

// ---------------- CSR count + graph histogram (merged) ----------------
__global__ void k_count_hist(const int* __restrict__ dst, const int* __restrict__ batch,
                             int E, int N, int* __restrict__ cnt, int* __restrict__ gcnt){
  int i = blockIdx.x*blockDim.x + threadIdx.x;
  if (i < E) atomicAdd(&cnt[dst[i]], 1);
  else if (i < E + N){
    int n = i - E;
    atomicAdd(&cnt[n], 1);              // self loop
    atomicAdd(&gcnt[batch[n]], 1);      // graph histogram
  }
}

__global__ void k_scan_block(const int* __restrict__ cnt, int* __restrict__ ex,
                             int* __restrict__ bsum, int N){
  __shared__ int tmp[256];
  int t = threadIdx.x;
  int i = blockIdx.x*256 + t;
  int v = (i < N) ? cnt[i] : 0;
  tmp[t] = v; __syncthreads();
  for (int off = 1; off < 256; off <<= 1){
    int u = (t >= off) ? tmp[t-off] : 0;
    __syncthreads();
    tmp[t] += u;
    __syncthreads();
  }
  if (i < N) ex[i] = tmp[t] - v;
  if (t == 255) bsum[blockIdx.x] = tmp[255];
}

__global__ void k_scan_tops(int* __restrict__ bsum, int nb){
  __shared__ int tmp[256];
  int t = threadIdx.x;
  int v = (t < nb) ? bsum[t] : 0;
  tmp[t] = v; __syncthreads();
  for (int off = 1; off < 256; off <<= 1){
    int u = (t >= off) ? tmp[t-off] : 0;
    __syncthreads();
    tmp[t] += u;
    __syncthreads();
  }
  if (t < nb) bsum[t] = tmp[t] - v;
}

__global__ void k_scan_add(int* __restrict__ row_start, const int* __restrict__ bsum,
                           int N, int total){
  int i = blockIdx.x*256 + threadIdx.x;
  if (i < N) row_start[i] += bsum[blockIdx.x];
  if (i == 0) row_start[N] = total;
}

__global__ void k_scatter(const int* __restrict__ src, const int* __restrict__ dst,
                          int E, int N, const int* __restrict__ row_start,
                          int* __restrict__ cursor, int* __restrict__ edge_src){
  int i = blockIdx.x*blockDim.x + threadIdx.x;
  if (i < E){
    int d = dst[i];
    int p = atomicAdd(&cursor[d], 1);
    edge_src[row_start[d] + p] = src[i];
  } else if (i < E + N){
    int n = i - E;
    int p = atomicAdd(&cursor[n], 1);
    edge_src[row_start[n] + p] = n;
  }
}

__global__ void k_gscan(const int* __restrict__ gcnt, int* __restrict__ goff,
                        int NG, int N){
  __shared__ int tmp[1024];
  int t = threadIdx.x;                 // blockDim = 1024
  int v = (t < NG) ? gcnt[t] : 0;
  tmp[t] = v; __syncthreads();
  for (int off = 1; off < 1024; off <<= 1){
    int u = (t >= off) ? tmp[t-off] : 0;
    __syncthreads();
    tmp[t] += u;
    __syncthreads();
  }
  if (t < NG) goff[t] = tmp[t] - v;
  if (t == 0) goff[NG] = N;
}

// ---------------- all-layer W split (shift/mask indexing, one launch) ----------------
// L1: 2*64*256 = 32768 elems -> WT1[512 rows][128]
// L2: 2*256*256 = 131072    -> WT2[512 rows][512]
// L3: 2*256*128 = 65536     -> WT3[256 rows][512]
__global__ void k_splitW_all(const float* __restrict__ Wl1, const float* __restrict__ Wr1,
                             const float* __restrict__ Wl2, const float* __restrict__ Wr2,
                             const float* __restrict__ Wl3, const float* __restrict__ Wr3,
                             _Float16* __restrict__ WT1, _Float16* __restrict__ WT2,
                             _Float16* __restrict__ WT3){
  int id = blockIdx.x*256 + threadIdx.x;
  if (id < 32768){
    int half = id >> 14, nk = id & 16383;
    int n = nk >> 6, k = nk & 63;
    const float* W = half ? Wr1 : Wl1;
    float w = W[(size_t)(k<<8) + n];
    _Float16 hh = (_Float16)w, ll = (_Float16)(w - (float)hh);
    size_t b = (size_t)((half<<8) + n)*128;
    WT1[b + k] = hh; WT1[b + 64 + k] = ll;
  } else if (id < 163840){
    int r = id - 32768;
    int half = r >> 16, nk = r & 65535;
    int n = nk >> 8, k = nk & 255;
    const float* W = half ? Wr2 : Wl2;
    float w = W[(size_t)(k<<8) + n];
    _Float16 hh = (_Float16)w, ll = (_Float16)(w - (float)hh);
    size_t b = (size_t)((half<<8) + n)*512;
    WT2[b + k] = hh; WT2[b + 256 + k] = ll;
  } else if (id < 229376){
    int r = id - 163840;
    int half = r >> 15, nk = r & 32767;
    int n = nk >> 8, k = nk & 255;
    const float* W = half ? Wr3 : Wl3;
    float w = W[(size_t)(k<<7) + n];
    _Float16 hh = (_Float16)w, ll = (_Float16)(w - (float)hh);
    size_t b = (size_t)((half<<7) + n)*512;
    WT3[b + k] = hh; WT3[b + 256 + k] = ll;
  }
}

// ---------------- x convert: x[N][K] fp32 -> X16[N][K] f16 ----------------
__global__ void k_cvt_x(const float* __restrict__ x, _Float16* __restrict__ X16,
                        int N, int K){
  int id = blockIdx.x*blockDim.x + threadIdx.x;
  int per = K/8;
  if (id >= N*per) return;
  int rr = id / per, c = (id % per)*8;
  fvec4 f0 = *(const fvec4*)&x[(size_t)rr*K + c];
  fvec4 f1 = *(const fvec4*)&x[(size_t)rr*K + c + 4];
  half8 hh;
  #pragma unroll
  for (int q = 0; q < 4; ++q){
    hh[q]   = (_Float16)f0[q];
    hh[4+q] = (_Float16)f1[q];
  }
  *(half8*)&X16[(size_t)rr*K + c] = hh;
}

// ---------------- 2-product f16 MFMA GEMM: C = A·Wh + A·Wl, BK=64 ----------------
// global_load_lds staging (width 16), linear LDS [128][64], XOR chunk swizzle.
__global__ __launch_bounds__(256, 3)
void k_gemm_split(const _Float16* __restrict__ A16, const _Float16* __restrict__ WT,
                  const float* __restrict__ biasL, const float* __restrict__ biasR,
                  _Float16* __restrict__ XL, _Float16* __restrict__ XR,
                  int M, int K, int NwHalf, int gy, int qq, int rr){
  __shared__ _Float16 sA [128*64];
  __shared__ _Float16 sWh[128*64];
  __shared__ _Float16 sWl[128*64];
  const int tid  = threadIdx.x;
  const int lane = tid & 63;
  const int wid  = tid >> 6;
  const int wm   = wid >> 1, wn = wid & 1;

  const int h   = blockIdx.x;
  const int xcd = h & 7, idx = h >> 3;
  const int l   = xcd*qq + (xcd < rr ? xcd : rr) + idx;
  const int bx  = l / gy, by = l - bx*gy;
  const int m0  = bx * 128;
  const int n0  = by * 128;
  const int ldw = 2*K;

  f32x4 acc[4][4];
  #pragma unroll
  for (int i = 0; i < 4; ++i)
    #pragma unroll
    for (int j = 0; j < 4; ++j)
      acc[i][j] = (f32x4){0.f,0.f,0.f,0.f};

  const int l15 = lane & 15;
  const int lhi = lane >> 4;
  const int sub = lane >> 3;   // 0..7
  const int cch = lane & 7;    // chunk 0..7

  const int nc = K/64;
  for (int c = 0; c < nc; ++c){
    const int kA = c*64;
    #pragma unroll
    for (int it = 0; it < 4; ++it){
      int r  = wid*32 + it*8 + sub;
      int cs = cch ^ (r & 7);
      const _Float16* ga = A16 + (size_t)(m0 + r)*K + kA + cs*8;
      const _Float16* gh = WT  + (size_t)(n0 + r)*ldw + kA + cs*8;
      const _Float16* gl = WT  + (size_t)(n0 + r)*ldw + K + kA + cs*8;
      int lb = (wid*32 + it*8)*64;
      __builtin_amdgcn_global_load_lds((gau32*)ga, (lau32*)&sA [lb], 16, 0, 0);
      __builtin_amdgcn_global_load_lds((gau32*)gh, (lau32*)&sWh[lb], 16, 0, 0);
      __builtin_amdgcn_global_load_lds((gau32*)gl, (lau32*)&sWl[lb], 16, 0, 0);
    }
    __syncthreads();
    #pragma unroll
    for (int ks = 0; ks < 2; ++ks){
      const int gc = (ks<<2) | lhi;
      half8 a[4], bh[4], bl[4];
      #pragma unroll
      for (int fm = 0; fm < 4; ++fm){
        int R = wm*64 + fm*16 + l15;
        a[fm] = *(const half8*)&sA[R*64 + (gc ^ (R&7))*8];
      }
      #pragma unroll
      for (int fn = 0; fn < 4; ++fn){
        int R = wn*64 + fn*16 + l15;
        int S = (gc ^ (R&7))*8;
        bh[fn] = *(const half8*)&sWh[R*64 + S];
        bl[fn] = *(const half8*)&sWl[R*64 + S];
      }
      #pragma unroll
      for (int fm = 0; fm < 4; ++fm)
        #pragma unroll
        for (int fn = 0; fn < 4; ++fn)
          acc[fm][fn] = __builtin_amdgcn_mfma_f32_16x16x32_f16(a[fm], bh[fn], acc[fm][fn], 0, 0, 0);
      #pragma unroll
      for (int fm = 0; fm < 4; ++fm)
        #pragma unroll
        for (int fn = 0; fn < 4; ++fn)
          acc[fm][fn] = __builtin_amdgcn_mfma_f32_16x16x32_f16(a[fm], bl[fn], acc[fm][fn], 0, 0, 0);
    }
    __syncthreads();
  }
  const bool isR = (n0 >= NwHalf);
  const float* bias = isR ? biasR : biasL;
  _Float16* Xo = isR ? XR : XL;
  const int nbase = isR ? (n0 - NwHalf) : n0;
  #pragma unroll
  for (int fm = 0; fm < 4; ++fm){
    #pragma unroll
    for (int fn = 0; fn < 4; ++fn){
      int cc = nbase + wn*64 + fn*16 + l15;
      float bv = bias[cc];
      #pragma unroll
      for (int q = 0; q < 4; ++q){
        int row = m0 + wm*64 + fm*16 + lhi*4 + q;
        if (row < M) Xo[(size_t)row*NwHalf + cc] = (_Float16)(acc[fm][fn][q] + bv);
      }
    }
  }
}

// ---------------- GATv2 aggregation v6: edge-slot split, 4-edge softmax batch ----------------
template<int HC, int C>
__global__ __launch_bounds__(256) void k_gat_agg(const _Float16* __restrict__ xl,
                                                 const _Float16* __restrict__ xr,
                                                 const float* __restrict__ att,
                                                 const float* __restrict__ bias,
                                                 const int* __restrict__ row_start,
                                                 const int* __restrict__ edge_src,
                                                 _Float16* __restrict__ outp,
                                                 int N, int apply_elu){
  constexpr int VEC   = 8;
  constexpr int LPE   = HC/VEC;    // lanes per edge (32 or 16)
  constexpr int EPW   = 64/LPE;    // edge slots per wave (2 or 4)
  constexpr int GROUP = C/VEC;     // lanes per head (8 or 16)
  const float M_INIT = -1.0e30f, T_INACT = -2.0e30f, THR = 11.54f; // ~8 nats

  int wid = (int)(((size_t)blockIdx.x * blockDim.x + threadIdx.x) >> 6);
  int lane = threadIdx.x & 63;
  if (wid >= N) return;
  const int h  = lane / LPE;                       // edge slot
  const int li = lane % LPE;
  const int ch = (li/GROUP)*C + (li%GROUP)*VEC;    // my channel base

  const _Float16 s16 = (_Float16)NEG_SLOPE;
  const half2v slope2 = {s16, s16};

  half2v attv2[4], xrr2[4];
  {
    fvec4 a0 = *(const fvec4*)&att[ch];
    fvec4 a1 = *(const fvec4*)&att[ch+4];
    const float L2E = 1.4426950408889634f;
    attv2[0][0]=(_Float16)(a0[0]*L2E); attv2[0][1]=(_Float16)(a0[1]*L2E);
    attv2[1][0]=(_Float16)(a0[2]*L2E); attv2[1][1]=(_Float16)(a0[3]*L2E);
    attv2[2][0]=(_Float16)(a1[0]*L2E); attv2[2][1]=(_Float16)(a1[1]*L2E);
    attv2[3][0]=(_Float16)(a1[2]*L2E); attv2[3][1]=(_Float16)(a1[3]*L2E);
    half8 hv = *(const half8*)&xr[(unsigned)(wid*HC) + ch];
    #pragma unroll
    for (int p = 0; p < 4; ++p){ xrr2[p][0] = hv[2*p]; xrr2[p][1] = hv[2*p+1]; }
  }

  float acc[VEC];
  #pragma unroll
  for (int q = 0; q < VEC; ++q) acc[q] = 0.f;
  float m = M_INIT, s = 0.f;

  const int e0   = row_start[wid];
  const int ecnt = row_start[wid+1] - e0;
  const _Float16* xlb = xl + ch;

  auto rowload = [&](int sn)->half8 {
    return *(const half8*)(xlb + (unsigned)(sn*HC));
  };
  auto logit1 = [&](half8 x8)->float{
    float t = 0.f;
    #pragma unroll
    for (int p = 0; p < 4; ++p){
      half2v xp; xp[0] = x8[2*p]; xp[1] = x8[2*p+1];
      half2v v  = xp + xrr2[p];
      half2v lv = __builtin_elementwise_max(v, v*slope2);   // leaky relu
      t = __builtin_amdgcn_fdot2(lv, attv2[p], t, false);
    }
    #pragma unroll
    for (int off = GROUP/2; off > 0; off >>= 1)
      t += __shfl_xor(t, off, 64);
    return t;
  };
  auto update4 = [&](float t0, float t1, float t2, float t3,
                     half8 x0, half8 x1, half8 x2, half8 x3){
    float pm = fmaxf(fmaxf(t0, t1), fmaxf(t2, t3));
    if (__all(pm <= m + THR)){
      float p0 = __builtin_amdgcn_exp2f(t0 - m);
      float p1 = __builtin_amdgcn_exp2f(t1 - m);
      float p2 = __builtin_amdgcn_exp2f(t2 - m);
      float p3 = __builtin_amdgcn_exp2f(t3 - m);
      s += (p0 + p1) + (p2 + p3);
      #pragma unroll
      for (int q = 0; q < VEC; ++q)
        acc[q] = fmaf(p0, (float)x0[q], fmaf(p1, (float)x1[q],
                 fmaf(p2, (float)x2[q], fmaf(p3, (float)x3[q], acc[q]))));
    } else {
      float nm = fmaxf(pm, m);
      float wo = __builtin_amdgcn_exp2f(m - nm);
      float p0 = __builtin_amdgcn_exp2f(t0 - nm);
      float p1 = __builtin_amdgcn_exp2f(t1 - nm);
      float p2 = __builtin_amdgcn_exp2f(t2 - nm);
      float p3 = __builtin_amdgcn_exp2f(t3 - nm);
      s = fmaf(s, wo, (p0 + p1) + (p2 + p3));
      m = nm;
      #pragma unroll
      for (int q = 0; q < VEC; ++q)
        acc[q] = fmaf(p0, (float)x0[q], fmaf(p1, (float)x1[q],
                 fmaf(p2, (float)x2[q], fmaf(p3, (float)x3[q], acc[q]*wo))));
    }
  };

  int base = e0 + h;
  const int R = ecnt / (4*EPW);
  for (int r = 0; r < R; ++r, base += 4*EPW){
    int s0 = edge_src[base];
    int s1 = edge_src[base + EPW];
    int s2 = edge_src[base + 2*EPW];
    int s3 = edge_src[base + 3*EPW];
    half8 x0 = rowload(s0), x1 = rowload(s1), x2 = rowload(s2), x3 = rowload(s3);
    float t0 = logit1(x0), t1 = logit1(x1), t2 = logit1(x2), t3 = logit1(x3);
    update4(t0, t1, t2, t3, x0, x1, x2, x3);
  }
  if (4*EPW*R < ecnt){               // one masked 4-edge tail (uniform)
    const int last = e0 + ecnt;
    bool a0 = base < last, a1 = base + EPW < last;
    bool a2 = base + 2*EPW < last, a3 = base + 3*EPW < last;
    int s0 = a0 ? edge_src[base] : 0;
    int s1 = a1 ? edge_src[base + EPW] : 0;
    int s2 = a2 ? edge_src[base + 2*EPW] : 0;
    int s3 = a3 ? edge_src[base + 3*EPW] : 0;
    half8 x0 = rowload(s0), x1 = rowload(s1), x2 = rowload(s2), x3 = rowload(s3);
    float t0 = logit1(x0); t0 = a0 ? t0 : T_INACT;
    float t1 = logit1(x1); t1 = a1 ? t1 : T_INACT;
    float t2 = logit1(x2); t2 = a2 ? t2 : T_INACT;
    float t3 = logit1(x3); t3 = a3 ? t3 : T_INACT;
    update4(t0, t1, t2, t3, x0, x1, x2, x3);
  }

  // merge edge-slot states (lanes ±LPE hold same channels)
  #pragma unroll
  for (int off = LPE; off < 64; off <<= 1){
    float mo = __shfl_xor(m, off, 64);
    float so = __shfl_xor(s, off, 64);
    float M  = fmaxf(m, mo);
    float w  = __builtin_amdgcn_exp2f(m  - M);
    float wo = __builtin_amdgcn_exp2f(mo - M);
    s = s*w + so*wo;
    #pragma unroll
    for (int q = 0; q < VEC; ++q)
      acc[q] = acc[q]*w + __shfl_xor(acc[q], off, 64)*wo;
    m = M;
  }

  if (h == 0){
    float inv = 1.f / s;
    fvec4 b0 = *(const fvec4*)&bias[ch];
    fvec4 b1 = *(const fvec4*)&bias[ch+4];
    half8 hh;
    #pragma unroll
    for (int q = 0; q < VEC; ++q){
      float o = acc[q]*inv + (q < 4 ? b0[q] : b1[q-4]);
      if (apply_elu) o = (o > 0.f) ? o : (__expf(o) - 1.f);
      hh[q] = (_Float16)o;
    }
    *(half8*)&outp[(unsigned)(wid*HC) + ch] = hh;
  }
}

// ---------------- segmented mean pool: one wave per graph (batch sorted) ----------------
__global__ __launch_bounds__(256) void k_pool_seg(const _Float16* __restrict__ h,
                                                  const int* __restrict__ goff,
                                                  const float* __restrict__ bias,
                                                  float* __restrict__ out, int NG){
  int g = (int)((blockIdx.x*blockDim.x + threadIdx.x) >> 6);
  int lane = threadIdx.x & 63;
  if (g >= NG) return;
  int s0 = goff[g], s1 = goff[g+1];
  float a0 = 0.f, a1 = 0.f;
  for (int n = s0; n < s1; ++n){
    half2v hv = *(const half2v*)&h[(unsigned)(n*128) + lane*2];
    a0 += (float)hv[0];
    a1 += (float)hv[1];
  }
  float inv = 1.f / fmaxf((float)(s1 - s0), 1.f);
  out[(unsigned)(g*128) + lane*2]     = a0*inv + bias[lane*2];
  out[(unsigned)(g*128) + lane*2 + 1] = a1*inv + bias[lane*2 + 1];
}

extern "C" void kernel_launch(void* const* d_in, const int* in_sizes, int n_in,
                              void* d_out, int out_size, void* d_ws, size_t ws_size,
                              hipStream_t stream){
  const float* x    = (const float*)d_in[0];
  const int*   ei   = (const int*)  d_in[1];
  const int*   batch= (const int*)  d_in[2];
  const float* Wl1  = (const float*)d_in[3];
  const float* bl1  = (const float*)d_in[4];
  const float* Wr1  = (const float*)d_in[5];
  const float* br1  = (const float*)d_in[6];
  const float* att1 = (const float*)d_in[7];
  const float* b1   = (const float*)d_in[8];
  const float* Wl2  = (const float*)d_in[9];
  const float* bl2  = (const float*)d_in[10];
  const float* Wr2  = (const float*)d_in[11];
  const float* br2  = (const float*)d_in[12];
  const float* att2 = (const float*)d_in[13];
  const float* b2   = (const float*)d_in[14];
  const float* Wl3  = (const float*)d_in[15];
  const float* bl3  = (const float*)d_in[16];
  const float* Wr3  = (const float*)d_in[17];
  const float* br3  = (const float*)d_in[18];
  const float* att3 = (const float*)d_in[19];
  const float* b3   = (const float*)d_in[20];

  int N  = in_sizes[2];          // 50000
  int E  = in_sizes[1] / 2;      // 800000
  int NG = out_size / 128;       // 1000
  const int* esrc = ei;
  const int* edst = ei + E;
  int Mpad = ((N + 127)/128)*128;

  size_t off = 0;
  char* base = (char*)d_ws;
  auto alloc = [&](size_t bytes)->void*{
    void* p = base + off;
    off += (bytes + 255) & ~(size_t)255;
    return p;
  };
  _Float16* XL  = (_Float16*)alloc((size_t)Mpad*256*sizeof(_Float16));
  _Float16* XR  = (_Float16*)alloc((size_t)Mpad*256*sizeof(_Float16));
  _Float16* H16 = (_Float16*)alloc((size_t)Mpad*256*sizeof(_Float16));
  _Float16* H3  = (_Float16*)alloc((size_t)Mpad*128*sizeof(_Float16));
  _Float16* X16 = (_Float16*)alloc((size_t)Mpad*64*sizeof(_Float16));
  _Float16* WT1 = (_Float16*)alloc((size_t)512*128*sizeof(_Float16));
  _Float16* WT2 = (_Float16*)alloc((size_t)512*512*sizeof(_Float16));
  _Float16* WT3 = (_Float16*)alloc((size_t)256*512*sizeof(_Float16));
  int* row_start = (int*)alloc(((size_t)N+1)*sizeof(int));
  int* edge_src  = (int*)alloc((size_t)(E+N)*sizeof(int));
  size_t cntpad  = ((size_t)N*sizeof(int) + 255) & ~(size_t)255;
  int* cnt       = (int*)alloc((size_t)N*sizeof(int));
  int* gcnt      = (int*)alloc((size_t)NG*sizeof(int));   // adjacent to cnt
  int* bsum      = (int*)alloc(256*sizeof(int));
  int* goff      = (int*)alloc(((size_t)NG+1)*sizeof(int));
  (void)ws_size; (void)n_in;

  int EN = E + N;
  int nb = (N + 255) / 256;

  // ---- prep: one memset covers cnt+gcnt (adjacent allocs) ----
  hipMemsetAsync(cnt, 0, cntpad + (size_t)NG*sizeof(int), stream);
  k_count_hist<<<(EN+255)/256, 256, 0, stream>>>(edst, batch, E, N, cnt, gcnt);
  k_scan_block<<<nb, 256, 0, stream>>>(cnt, row_start, bsum, N);
  k_scan_tops<<<1, 256, 0, stream>>>(bsum, nb);
  k_scan_add<<<nb, 256, 0, stream>>>(row_start, bsum, N, EN);
  hipMemsetAsync(cnt, 0, (size_t)N*sizeof(int), stream);   // cursor reset
  k_scatter<<<(EN+255)/256, 256, 0, stream>>>(esrc, edst, E, N, row_start, cnt, edge_src);
  k_gscan<<<1, 1024, 0, stream>>>(gcnt, goff, NG, N);
  k_splitW_all<<<229376/256, 256, 0, stream>>>(Wl1, Wr1, Wl2, Wr2, Wl3, Wr3, WT1, WT2, WT3);
  k_cvt_x<<<((N*8)+255)/256, 256, 0, stream>>>(x, X16, N, 64);

  dim3 blk(256);
  int agg_blocks = (N + 3) / 4;
  int gx = Mpad/128;             // 391
  int G1 = gx*4;                 // layers 1,2: 512 cols
  int G3 = gx*2;                 // layer 3: 256 cols

  // ---- Layer 1: K=64 -> 4x64 ----
  k_gemm_split<<<G1, blk, 0, stream>>>(X16, WT1, bl1, br1, XL, XR, N, 64, 256, 4, G1/8, G1%8);
  k_gat_agg<256,64><<<agg_blocks, blk, 0, stream>>>(XL, XR, att1, b1, row_start, edge_src, H16, N, 1);

  // ---- Layer 2: K=256 -> 4x64 ----
  k_gemm_split<<<G1, blk, 0, stream>>>(H16, WT2, bl2, br2, XL, XR, N, 256, 256, 4, G1/8, G1%8);
  k_gat_agg<256,64><<<agg_blocks, blk, 0, stream>>>(XL, XR, att2, b2, row_start, edge_src, H16, N, 1);

  // ---- Layer 3: K=256 -> 128, 1 head ----
  k_gemm_split<<<G3, blk, 0, stream>>>(H16, WT3, bl3, br3, XL, XR, N, 256, 128, 2, G3/8, G3%8);
  k_gat_agg<128,128><<<agg_blocks, blk, 0, stream>>>(XL, XR, att3, b3, row_start, edge_src, H3, N, 0);

  // ---- segmented mean pool + bias ----
  k_pool_seg<<<(NG+3)/4, blk, 0, stream>>>(H3, goff, b3, (float*)d_out, NG);
}

// Round 13
// 439.426 us; speedup vs baseline: 1.0053x; 1.0053x over previous
//
#include <hip/hip_runtime.h>
#include <math.h>

#define NEG_SLOPE 0.2f

typedef _Float16 half8 __attribute__((ext_vector_type(8)));
typedef _Float16 half4 __attribute__((ext_vector_type(4)));
typedef _Float16 half2v __attribute__((ext_vector_type(2)));
typedef float    f32x4 __attribute__((ext_vector_type(4)));
typedef float    fvec4 __attribute__((ext_vector_type(4)));
typedef float    fvec2 __attribute__((ext_vector_type(2)));

typedef __attribute__((address_space(1))) const unsigned int gau32;
typedef __attribute__((address_space(3))) unsigned int lau32;

// ---------------- CSR count + graph histogram (merged) ----------------
__global__ void k_count_hist(const int* __restrict__ dst, const int* __restrict__ batch,
                             int E, int N, int* __restrict__ cnt, int* __restrict__ gcnt){
  int i = blockIdx.x*blockDim.x + threadIdx.x;
  if (i < E) atomicAdd(&cnt[dst[i]], 1);
  else if (i < E + N){
    int n = i - E;
    atomicAdd(&cnt[n], 1);              // self loop
    atomicAdd(&gcnt[batch[n]], 1);      // graph histogram
  }
}

__global__ void k_scan_block(const int* __restrict__ cnt, int* __restrict__ ex,
                             int* __restrict__ bsum, int N){
  __shared__ int tmp[256];
  int t = threadIdx.x;
  int i = blockIdx.x*256 + t;
  int v = (i < N) ? cnt[i] : 0;
  tmp[t] = v; __syncthreads();
  for (int off = 1; off < 256; off <<= 1){
    int u = (t >= off) ? tmp[t-off] : 0;
    __syncthreads();
    tmp[t] += u;
    __syncthreads();
  }
  if (i < N) ex[i] = tmp[t] - v;
  if (t == 255) bsum[blockIdx.x] = tmp[255];
}

__global__ void k_scan_tops(int* __restrict__ bsum, int nb){
  __shared__ int tmp[256];
  int t = threadIdx.x;
  int v = (t < nb) ? bsum[t] : 0;
  tmp[t] = v; __syncthreads();
  for (int off = 1; off < 256; off <<= 1){
    int u = (t >= off) ? tmp[t-off] : 0;
    __syncthreads();
    tmp[t] += u;
    __syncthreads();
  }
  if (t < nb) bsum[t] = tmp[t] - v;
}

__global__ void k_scan_add(int* __restrict__ row_start, const int* __restrict__ bsum,
                           int N, int total){
  int i = blockIdx.x*256 + threadIdx.x;
  if (i < N) row_start[i] += bsum[blockIdx.x];
  if (i == 0) row_start[N] = total;
}

__global__ void k_scatter(const int* __restrict__ src, const int* __restrict__ dst,
                          int E, int N, const int* __restrict__ row_start,
                          int* __restrict__ cursor, int* __restrict__ edge_src){
  int i = blockIdx.x*blockDim.x + threadIdx.x;
  if (i < E){
    int d = dst[i];
    int p = atomicAdd(&cursor[d], 1);
    edge_src[row_start[d] + p] = src[i];
  } else if (i < E + N){
    int n = i - E;
    int p = atomicAdd(&cursor[n], 1);
    edge_src[row_start[n] + p] = n;
  }
}

__global__ void k_gscan(const int* __restrict__ gcnt, int* __restrict__ goff,
                        int NG, int N){
  __shared__ int tmp[1024];
  int t = threadIdx.x;                 // blockDim = 1024
  int v = (t < NG) ? gcnt[t] : 0;
  tmp[t] = v; __syncthreads();
  for (int off = 1; off < 1024; off <<= 1){
    int u = (t >= off) ? tmp[t-off] : 0;
    __syncthreads();
    tmp[t] += u;
    __syncthreads();
  }
  if (t < NG) goff[t] = tmp[t] - v;
  if (t == 0) goff[NG] = N;
}

// ---------------- all-layer W split (shift/mask indexing, one launch) ----------------
__global__ void k_splitW_all(const float* __restrict__ Wl1, const float* __restrict__ Wr1,
                             const float* __restrict__ Wl2, const float* __restrict__ Wr2,
                             const float* __restrict__ Wl3, const float* __restrict__ Wr3,
                             _Float16* __restrict__ WT1, _Float16* __restrict__ WT2,
                             _Float16* __restrict__ WT3){
  int id = blockIdx.x*256 + threadIdx.x;
  if (id < 32768){
    int half = id >> 14, nk = id & 16383;
    int n = nk >> 6, k = nk & 63;
    const float* W = half ? Wr1 : Wl1;
    float w = W[(size_t)(k<<8) + n];
    _Float16 hh = (_Float16)w, ll = (_Float16)(w - (float)hh);
    size_t b = (size_t)((half<<8) + n)*128;
    WT1[b + k] = hh; WT1[b + 64 + k] = ll;
  } else if (id < 163840){
    int r = id - 32768;
    int half = r >> 16, nk = r & 65535;
    int n = nk >> 8, k = nk & 255;
    const float* W = half ? Wr2 : Wl2;
    float w = W[(size_t)(k<<8) + n];
    _Float16 hh = (_Float16)w, ll = (_Float16)(w - (float)hh);
    size_t b = (size_t)((half<<8) + n)*512;
    WT2[b + k] = hh; WT2[b + 256 + k] = ll;
  } else if (id < 229376){
    int r = id - 163840;
    int half = r >> 15, nk = r & 32767;
    int n = nk >> 8, k = nk & 255;
    const float* W = half ? Wr3 : Wl3;
    float w = W[(size_t)(k<<7) + n];
    _Float16 hh = (_Float16)w, ll = (_Float16)(w - (float)hh);
    size_t b = (size_t)((half<<7) + n)*512;
    WT3[b + k] = hh; WT3[b + 256 + k] = ll;
  }
}

// ---------------- x convert: x[N][K] fp32 -> X16[N][K] f16 ----------------
__global__ void k_cvt_x(const float* __restrict__ x, _Float16* __restrict__ X16,
                        int N, int K){
  int id = blockIdx.x*blockDim.x + threadIdx.x;
  int per = K/8;
  if (id >= N*per) return;
  int rr = id / per, c = (id % per)*8;
  fvec4 f0 = *(const fvec4*)&x[(size_t)rr*K + c];
  fvec4 f1 = *(const fvec4*)&x[(size_t)rr*K + c + 4];
  half8 hh;
  #pragma unroll
  for (int q = 0; q < 4; ++q){
    hh[q]   = (_Float16)f0[q];
    hh[4+q] = (_Float16)f1[q];
  }
  *(half8*)&X16[(size_t)rr*K + c] = hh;
}

// ---------------- 2-product f16 MFMA GEMM: C = A·Wh + A·Wl, BK=64 ----------------
// global_load_lds staging (width 16), linear LDS [128][64], XOR chunk swizzle.
__global__ __launch_bounds__(256, 3)
void k_gemm_split(const _Float16* __restrict__ A16, const _Float16* __restrict__ WT,
                  const float* __restrict__ biasL, const float* __restrict__ biasR,
                  _Float16* __restrict__ XL, _Float16* __restrict__ XR,
                  int M, int K, int NwHalf, int gy, int qq, int rr){
  __shared__ _Float16 sA [128*64];
  __shared__ _Float16 sWh[128*64];
  __shared__ _Float16 sWl[128*64];
  const int tid  = threadIdx.x;
  const int lane = tid & 63;
  const int wid  = tid >> 6;
  const int wm   = wid >> 1, wn = wid & 1;

  const int h   = blockIdx.x;
  const int xcd = h & 7, idx = h >> 3;
  const int l   = xcd*qq + (xcd < rr ? xcd : rr) + idx;
  const int bx  = l / gy, by = l - bx*gy;
  const int m0  = bx * 128;
  const int n0  = by * 128;
  const int ldw = 2*K;

  f32x4 acc[4][4];
  #pragma unroll
  for (int i = 0; i < 4; ++i)
    #pragma unroll
    for (int j = 0; j < 4; ++j)
      acc[i][j] = (f32x4){0.f,0.f,0.f,0.f};

  const int l15 = lane & 15;
  const int lhi = lane >> 4;
  const int sub = lane >> 3;   // 0..7
  const int cch = lane & 7;    // chunk 0..7

  const int nc = K/64;
  for (int c = 0; c < nc; ++c){
    const int kA = c*64;
    #pragma unroll
    for (int it = 0; it < 4; ++it){
      int r  = wid*32 + it*8 + sub;
      int cs = cch ^ (r & 7);
      const _Float16* ga = A16 + (size_t)(m0 + r)*K + kA + cs*8;
      const _Float16* gh = WT  + (size_t)(n0 + r)*ldw + kA + cs*8;
      const _Float16* gl = WT  + (size_t)(n0 + r)*ldw + K + kA + cs*8;
      int lb = (wid*32 + it*8)*64;
      __builtin_amdgcn_global_load_lds((gau32*)ga, (lau32*)&sA [lb], 16, 0, 0);
      __builtin_amdgcn_global_load_lds((gau32*)gh, (lau32*)&sWh[lb], 16, 0, 0);
      __builtin_amdgcn_global_load_lds((gau32*)gl, (lau32*)&sWl[lb], 16, 0, 0);
    }
    __syncthreads();
    #pragma unroll
    for (int ks = 0; ks < 2; ++ks){
      const int gc = (ks<<2) | lhi;
      half8 a[4], bh[4], bl[4];
      #pragma unroll
      for (int fm = 0; fm < 4; ++fm){
        int R = wm*64 + fm*16 + l15;
        a[fm] = *(const half8*)&sA[R*64 + (gc ^ (R&7))*8];
      }
      #pragma unroll
      for (int fn = 0; fn < 4; ++fn){
        int R = wn*64 + fn*16 + l15;
        int S = (gc ^ (R&7))*8;
        bh[fn] = *(const half8*)&sWh[R*64 + S];
        bl[fn] = *(const half8*)&sWl[R*64 + S];
      }
      #pragma unroll
      for (int fm = 0; fm < 4; ++fm)
        #pragma unroll
        for (int fn = 0; fn < 4; ++fn)
          acc[fm][fn] = __builtin_amdgcn_mfma_f32_16x16x32_f16(a[fm], bh[fn], acc[fm][fn], 0, 0, 0);
      #pragma unroll
      for (int fm = 0; fm < 4; ++fm)
        #pragma unroll
        for (int fn = 0; fn < 4; ++fn)
          acc[fm][fn] = __builtin_amdgcn_mfma_f32_16x16x32_f16(a[fm], bl[fn], acc[fm][fn], 0, 0, 0);
    }
    __syncthreads();
  }
  const bool isR = (n0 >= NwHalf);
  const float* bias = isR ? biasR : biasL;
  _Float16* Xo = isR ? XR : XL;
  const int nbase = isR ? (n0 - NwHalf) : n0;
  #pragma unroll
  for (int fm = 0; fm < 4; ++fm){
    #pragma unroll
    for (int fn = 0; fn < 4; ++fn){
      int cc = nbase + wn*64 + fn*16 + l15;
      float bv = bias[cc];
      #pragma unroll
      for (int q = 0; q < 4; ++q){
        int row = m0 + wm*64 + fm*16 + lhi*4 + q;
        if (row < M) Xo[(size_t)row*NwHalf + cc] = (_Float16)(acc[fm][fn][q] + bv);
      }
    }
  }
}

// ---------------- GATv2 aggregation v7: persistent waves, interleaved nodes ----------------
// Wave w processes nodes w, w+W, w+2W... (W = total waves). update2 softmax (r11 shape).
template<int HC, int C>
__global__ __launch_bounds__(256) void k_gat_agg(const _Float16* __restrict__ xl,
                                                 const _Float16* __restrict__ xr,
                                                 const float* __restrict__ att,
                                                 const float* __restrict__ bias,
                                                 const int* __restrict__ row_start,
                                                 const int* __restrict__ edge_src,
                                                 _Float16* __restrict__ outp,
                                                 int N, int apply_elu, int totw){
  constexpr int VEC   = 8;
  constexpr int LPE   = HC/VEC;    // lanes per edge (32 or 16)
  constexpr int EPW   = 64/LPE;    // edge slots per wave (2 or 4)
  constexpr int GROUP = C/VEC;     // lanes per head (8 or 16)
  const float M_INIT = -1.0e30f, T_INACT = -2.0e30f, THR = 11.54f; // ~8 nats

  const int gw   = (int)(((size_t)blockIdx.x * blockDim.x + threadIdx.x) >> 6);
  const int lane = threadIdx.x & 63;
  const int h  = lane / LPE;                       // edge slot
  const int li = lane % LPE;
  const int ch = (li/GROUP)*C + (li%GROUP)*VEC;    // my channel base

  const _Float16 s16 = (_Float16)NEG_SLOPE;
  const half2v slope2 = {s16, s16};

  // node-independent: att pre-scaled by log2e (hoisted out of node loop)
  half2v attv2[4];
  {
    fvec4 a0 = *(const fvec4*)&att[ch];
    fvec4 a1 = *(const fvec4*)&att[ch+4];
    const float L2E = 1.4426950408889634f;
    attv2[0][0]=(_Float16)(a0[0]*L2E); attv2[0][1]=(_Float16)(a0[1]*L2E);
    attv2[1][0]=(_Float16)(a0[2]*L2E); attv2[1][1]=(_Float16)(a0[3]*L2E);
    attv2[2][0]=(_Float16)(a1[0]*L2E); attv2[2][1]=(_Float16)(a1[1]*L2E);
    attv2[3][0]=(_Float16)(a1[2]*L2E); attv2[3][1]=(_Float16)(a1[3]*L2E);
  }
  const _Float16* xlb = xl + ch;

  for (int wid = gw; wid < N; wid += totw){
    half2v xrr2[4];
    {
      half8 hv = *(const half8*)&xr[(unsigned)(wid*HC) + ch];
      #pragma unroll
      for (int p = 0; p < 4; ++p){ xrr2[p][0] = hv[2*p]; xrr2[p][1] = hv[2*p+1]; }
    }
    float acc[VEC];
    #pragma unroll
    for (int q = 0; q < VEC; ++q) acc[q] = 0.f;
    float m = M_INIT, s = 0.f;

    const int e0   = row_start[wid];
    const int ecnt = row_start[wid+1] - e0;

    auto rowload = [&](int sn)->half8 {
      return *(const half8*)(xlb + (unsigned)(sn*HC));
    };
    auto logit1 = [&](half8 x8)->float{
      float t = 0.f;
      #pragma unroll
      for (int p = 0; p < 4; ++p){
        half2v xp; xp[0] = x8[2*p]; xp[1] = x8[2*p+1];
        half2v v  = xp + xrr2[p];
        half2v lv = __builtin_elementwise_max(v, v*slope2);   // leaky relu
        t = __builtin_amdgcn_fdot2(lv, attv2[p], t, false);
      }
      #pragma unroll
      for (int off = GROUP/2; off > 0; off >>= 1)
        t += __shfl_xor(t, off, 64);
      return t;
    };
    auto update2 = [&](float ta, float tb, half8 xa, half8 xb){
      float pm = fmaxf(ta, tb);
      if (__all(pm <= m + THR)){
        float pa = __builtin_amdgcn_exp2f(ta - m);
        float pb = __builtin_amdgcn_exp2f(tb - m);
        s += pa + pb;
        #pragma unroll
        for (int q = 0; q < VEC; ++q)
          acc[q] = fmaf(pa, (float)xa[q], fmaf(pb, (float)xb[q], acc[q]));
      } else {
        float nm = fmaxf(pm, m);
        float wo = __builtin_amdgcn_exp2f(m - nm);
        float pa = __builtin_amdgcn_exp2f(ta - nm);
        float pb = __builtin_amdgcn_exp2f(tb - nm);
        s = fmaf(s, wo, pa + pb);
        m = nm;
        #pragma unroll
        for (int q = 0; q < VEC; ++q)
          acc[q] = fmaf(pa, (float)xa[q], fmaf(pb, (float)xb[q], acc[q]*wo));
      }
    };

    int base = e0 + h;
    const int R = ecnt / (2*EPW);
    for (int r = 0; r < R; ++r, base += 2*EPW){
      int sa = edge_src[base];
      int sb = edge_src[base + EPW];
      half8 xa = rowload(sa);
      half8 xb = rowload(sb);
      float ta = logit1(xa);
      float tb = logit1(xb);
      update2(ta, tb, xa, xb);
    }
    if (2*EPW*R < ecnt){               // predicated tail pair (uniform branch)
      const int last = e0 + ecnt;
      bool a1 = base < last, a2 = base + EPW < last;
      int sa = a1 ? edge_src[base] : 0;
      int sb = a2 ? edge_src[base + EPW] : 0;
      half8 xa = rowload(sa);
      half8 xb = rowload(sb);
      float ta = logit1(xa); ta = a1 ? ta : T_INACT;
      float tb = logit1(xb); tb = a2 ? tb : T_INACT;
      update2(ta, tb, xa, xb);
    }

    // merge edge-slot states (lanes ±LPE hold same channels)
    #pragma unroll
    for (int off = LPE; off < 64; off <<= 1){
      float mo = __shfl_xor(m, off, 64);
      float so = __shfl_xor(s, off, 64);
      float M  = fmaxf(m, mo);
      float w  = __builtin_amdgcn_exp2f(m  - M);
      float wo = __builtin_amdgcn_exp2f(mo - M);
      s = s*w + so*wo;
      #pragma unroll
      for (int q = 0; q < VEC; ++q)
        acc[q] = acc[q]*w + __shfl_xor(acc[q], off, 64)*wo;
      m = M;
    }

    if (h == 0){
      float inv = 1.f / s;
      fvec4 b0 = *(const fvec4*)&bias[ch];
      fvec4 b1 = *(const fvec4*)&bias[ch+4];
      half8 hh;
      #pragma unroll
      for (int q = 0; q < VEC; ++q){
        float o = acc[q]*inv + (q < 4 ? b0[q] : b1[q-4]);
        if (apply_elu) o = (o > 0.f) ? o : (__expf(o) - 1.f);
        hh[q] = (_Float16)o;
      }
      *(half8*)&outp[(unsigned)(wid*HC) + ch] = hh;
    }
  }
}

// ---------------- segmented mean pool: one wave per graph (batch sorted) ----------------
__global__ __launch_bounds__(256) void k_pool_seg(const _Float16* __restrict__ h,
                                                  const int* __restrict__ goff,
                                                  const float* __restrict__ bias,
                                                  float* __restrict__ out, int NG){
  int g = (int)((blockIdx.x*blockDim.x + threadIdx.x) >> 6);
  int lane = threadIdx.x & 63;
  if (g >= NG) return;
  int s0 = goff[g], s1 = goff[g+1];
  float a0 = 0.f, a1 = 0.f;
  for (int n = s0; n < s1; ++n){
    half2v hv = *(const half2v*)&h[(unsigned)(n*128) + lane*2];
    a0 += (float)hv[0];
    a1 += (float)hv[1];
  }
  float inv = 1.f / fmaxf((float)(s1 - s0), 1.f);
  out[(unsigned)(g*128) + lane*2]     = a0*inv + bias[lane*2];
  out[(unsigned)(g*128) + lane*2 + 1] = a1*inv + bias[lane*2 + 1];
}

extern "C" void kernel_launch(void* const* d_in, const int* in_sizes, int n_in,
                              void* d_out, int out_size, void* d_ws, size_t ws_size,
                              hipStream_t stream){
  const float* x    = (const float*)d_in[0];
  const int*   ei   = (const int*)  d_in[1];
  const int*   batch= (const int*)  d_in[2];
  const float* Wl1  = (const float*)d_in[3];
  const float* bl1  = (const float*)d_in[4];
  const float* Wr1  = (const float*)d_in[5];
  const float* br1  = (const float*)d_in[6];
  const float* att1 = (const float*)d_in[7];
  const float* b1   = (const float*)d_in[8];
  const float* Wl2  = (const float*)d_in[9];
  const float* bl2  = (const float*)d_in[10];
  const float* Wr2  = (const float*)d_in[11];
  const float* br2  = (const float*)d_in[12];
  const float* att2 = (const float*)d_in[13];
  const float* b2   = (const float*)d_in[14];
  const float* Wl3  = (const float*)d_in[15];
  const float* bl3  = (const float*)d_in[16];
  const float* Wr3  = (const float*)d_in[17];
  const float* br3  = (const float*)d_in[18];
  const float* att3 = (const float*)d_in[19];
  const float* b3   = (const float*)d_in[20];

  int N  = in_sizes[2];          // 50000
  int E  = in_sizes[1] / 2;      // 800000
  int NG = out_size / 128;       // 1000
  const int* esrc = ei;
  const int* edst = ei + E;
  int Mpad = ((N + 127)/128)*128;

  size_t off = 0;
  char* base = (char*)d_ws;
  auto alloc = [&](size_t bytes)->void*{
    void* p = base + off;
    off += (bytes + 255) & ~(size_t)255;
    return p;
  };
  _Float16* XL  = (_Float16*)alloc((size_t)Mpad*256*sizeof(_Float16));
  _Float16* XR  = (_Float16*)alloc((size_t)Mpad*256*sizeof(_Float16));
  _Float16* H16 = (_Float16*)alloc((size_t)Mpad*256*sizeof(_Float16));
  _Float16* H3  = (_Float16*)alloc((size_t)Mpad*128*sizeof(_Float16));
  _Float16* X16 = (_Float16*)alloc((size_t)Mpad*64*sizeof(_Float16));
  _Float16* WT1 = (_Float16*)alloc((size_t)512*128*sizeof(_Float16));
  _Float16* WT2 = (_Float16*)alloc((size_t)512*512*sizeof(_Float16));
  _Float16* WT3 = (_Float16*)alloc((size_t)256*512*sizeof(_Float16));
  int* row_start = (int*)alloc(((size_t)N+1)*sizeof(int));
  int* edge_src  = (int*)alloc((size_t)(E+N)*sizeof(int));
  size_t cntpad  = ((size_t)N*sizeof(int) + 255) & ~(size_t)255;
  int* cnt       = (int*)alloc((size_t)N*sizeof(int));
  int* gcnt      = (int*)alloc((size_t)NG*sizeof(int));   // adjacent to cnt
  int* bsum      = (int*)alloc(256*sizeof(int));
  int* goff      = (int*)alloc(((size_t)NG+1)*sizeof(int));
  (void)ws_size; (void)n_in;

  int EN = E + N;
  int nb = (N + 255) / 256;

  // ---- prep: one memset covers cnt+gcnt (adjacent allocs) ----
  hipMemsetAsync(cnt, 0, cntpad + (size_t)NG*sizeof(int), stream);
  k_count_hist<<<(EN+255)/256, 256, 0, stream>>>(edst, batch, E, N, cnt, gcnt);
  k_scan_block<<<nb, 256, 0, stream>>>(cnt, row_start, bsum, N);
  k_scan_tops<<<1, 256, 0, stream>>>(bsum, nb);
  k_scan_add<<<nb, 256, 0, stream>>>(row_start, bsum, N, EN);
  hipMemsetAsync(cnt, 0, (size_t)N*sizeof(int), stream);   // cursor reset
  k_scatter<<<(EN+255)/256, 256, 0, stream>>>(esrc, edst, E, N, row_start, cnt, edge_src);
  k_gscan<<<1, 1024, 0, stream>>>(gcnt, goff, NG, N);
  k_splitW_all<<<229376/256, 256, 0, stream>>>(Wl1, Wr1, Wl2, Wr2, Wl3, Wr3, WT1, WT2, WT3);
  k_cvt_x<<<((N*8)+255)/256, 256, 0, stream>>>(x, X16, N, 64);

  dim3 blk(256);
  int agg_blocks = 1536;              // persistent waves: 6144 waves, ~24/CU
  int totw = agg_blocks*4;
  int gx = Mpad/128;                  // 391
  int G1 = gx*4;                      // layers 1,2: 512 cols
  int G3 = gx*2;                      // layer 3: 256 cols

  // ---- Layer 1: K=64 -> 4x64 ----
  k_gemm_split<<<G1, blk, 0, stream>>>(X16, WT1, bl1, br1, XL, XR, N, 64, 256, 4, G1/8, G1%8);
  k_gat_agg<256,64><<<agg_blocks, blk, 0, stream>>>(XL, XR, att1, b1, row_start, edge_src, H16, N, 1, totw);

  // ---- Layer 2: K=256 -> 4x64 ----
  k_gemm_split<<<G1, blk, 0, stream>>>(H16, WT2, bl2, br2, XL, XR, N, 256, 256, 4, G1/8, G1%8);
  k_gat_agg<256,64><<<agg_blocks, blk, 0, stream>>>(XL, XR, att2, b2, row_start, edge_src, H16, N, 1, totw);

  // ---- Layer 3: K=256 -> 128, 1 head ----
  k_gemm_split<<<G3, blk, 0, stream>>>(H16, WT3, bl3, br3, XL, XR, N, 256, 128, 2, G3/8, G3%8);
  k_gat_agg<128,128><<<agg_blocks, blk, 0, stream>>>(XL, XR, att3, b3, row_start, edge_src, H3, N, 0, totw);

  // ---- segmented mean pool + bias ----
  k_pool_seg<<<(NG+3)/4, blk, 0, stream>>>(H3, goff, b3, (float*)d_out, NG);
}

// Round 14
// 422.243 us; speedup vs baseline: 1.0462x; 1.0407x over previous
//
#include <hip/hip_runtime.h>
#include <math.h>

#define NEG_SLOPE 0.2f

typedef _Float16 half8 __attribute__((ext_vector_type(8)));
typedef _Float16 half4 __attribute__((ext_vector_type(4)));
typedef _Float16 half2v __attribute__((ext_vector_type(2)));
typedef float    f32x4 __attribute__((ext_vector_type(4)));
typedef float    fvec4 __attribute__((ext_vector_type(4)));
typedef float    fvec2 __attribute__((ext_vector_type(2)));

typedef __attribute__((address_space(1))) const unsigned int gau32;
typedef __attribute__((address_space(3))) unsigned int lau32;

// ---------------- fused prep: count+hist | W-split(all) | x-convert ----------------
// block ranges: [0,nbCH) count+hist, [nbCH,nbCH+896) W split, rest cvt_x
__global__ void k_prep(const int* __restrict__ edst, const int* __restrict__ batch,
                       int E, int N, int* __restrict__ cnt, int* __restrict__ gcnt,
                       const float* __restrict__ Wl1, const float* __restrict__ Wr1,
                       const float* __restrict__ Wl2, const float* __restrict__ Wr2,
                       const float* __restrict__ Wl3, const float* __restrict__ Wr3,
                       _Float16* __restrict__ WT1, _Float16* __restrict__ WT2,
                       _Float16* __restrict__ WT3,
                       const float* __restrict__ x, _Float16* __restrict__ X16,
                       int nbCH, int nbSW){
  int b = blockIdx.x;
  int t = threadIdx.x;
  if (b < nbCH){
    int i = b*256 + t;
    if (i < E) atomicAdd(&cnt[edst[i]], 1);
    else if (i < E + N){
      int n = i - E;
      atomicAdd(&cnt[n], 1);              // self loop
      atomicAdd(&gcnt[batch[n]], 1);      // graph histogram
    }
  } else if (b < nbCH + nbSW){
    int id = (b - nbCH)*256 + t;
    if (id < 32768){
      int half = id >> 14, nk = id & 16383;
      int n = nk >> 6, k = nk & 63;
      const float* W = half ? Wr1 : Wl1;
      float w = W[(size_t)(k<<8) + n];
      _Float16 hh = (_Float16)w, ll = (_Float16)(w - (float)hh);
      size_t bb = (size_t)((half<<8) + n)*128;
      WT1[bb + k] = hh; WT1[bb + 64 + k] = ll;
    } else if (id < 163840){
      int r = id - 32768;
      int half = r >> 16, nk = r & 65535;
      int n = nk >> 8, k = nk & 255;
      const float* W = half ? Wr2 : Wl2;
      float w = W[(size_t)(k<<8) + n];
      _Float16 hh = (_Float16)w, ll = (_Float16)(w - (float)hh);
      size_t bb = (size_t)((half<<8) + n)*512;
      WT2[bb + k] = hh; WT2[bb + 256 + k] = ll;
    } else if (id < 229376){
      int r = id - 163840;
      int half = r >> 15, nk = r & 32767;
      int n = nk >> 8, k = nk & 255;
      const float* W = half ? Wr3 : Wl3;
      float w = W[(size_t)(k<<7) + n];
      _Float16 hh = (_Float16)w, ll = (_Float16)(w - (float)hh);
      size_t bb = (size_t)((half<<7) + n)*512;
      WT3[bb + k] = hh; WT3[bb + 256 + k] = ll;
    }
  } else {
    int id = (b - nbCH - nbSW)*256 + t;      // x convert, K=64: 8 elems/thread
    if (id < N*8){
      int rr = id >> 3, c = (id & 7)*8;
      fvec4 f0 = *(const fvec4*)&x[(size_t)rr*64 + c];
      fvec4 f1 = *(const fvec4*)&x[(size_t)rr*64 + c + 4];
      half8 hh;
      #pragma unroll
      for (int q = 0; q < 4; ++q){
        hh[q]   = (_Float16)f0[q];
        hh[4+q] = (_Float16)f1[q];
      }
      *(half8*)&X16[(size_t)rr*64 + c] = hh;
    }
  }
}

__global__ void k_scan_block(const int* __restrict__ cnt, int* __restrict__ ex,
                             int* __restrict__ bsum, int N){
  __shared__ int tmp[256];
  int t = threadIdx.x;
  int i = blockIdx.x*256 + t;
  int v = (i < N) ? cnt[i] : 0;
  tmp[t] = v; __syncthreads();
  for (int off = 1; off < 256; off <<= 1){
    int u = (t >= off) ? tmp[t-off] : 0;
    __syncthreads();
    tmp[t] += u;
    __syncthreads();
  }
  if (i < N) ex[i] = tmp[t] - v;
  if (t == 255) bsum[blockIdx.x] = tmp[255];
}

__global__ void k_scan_tops(int* __restrict__ bsum, int nb){
  __shared__ int tmp[256];
  int t = threadIdx.x;
  int v = (t < nb) ? bsum[t] : 0;
  tmp[t] = v; __syncthreads();
  for (int off = 1; off < 256; off <<= 1){
    int u = (t >= off) ? tmp[t-off] : 0;
    __syncthreads();
    tmp[t] += u;
    __syncthreads();
  }
  if (t < nb) bsum[t] = tmp[t] - v;
}

__global__ void k_scan_add(int* __restrict__ row_start, const int* __restrict__ bsum,
                           int N, int total){
  int i = blockIdx.x*256 + threadIdx.x;
  if (i < N) row_start[i] += bsum[blockIdx.x];
  if (i == 0) row_start[N] = total;
}

__global__ void k_scatter(const int* __restrict__ src, const int* __restrict__ dst,
                          int E, int N, const int* __restrict__ row_start,
                          int* __restrict__ cursor, int* __restrict__ edge_src){
  int i = blockIdx.x*blockDim.x + threadIdx.x;
  if (i < E){
    int d = dst[i];
    int p = atomicAdd(&cursor[d], 1);
    edge_src[row_start[d] + p] = src[i];
  } else if (i < E + N){
    int n = i - E;
    int p = atomicAdd(&cursor[n], 1);
    edge_src[row_start[n] + p] = n;
  }
}

__global__ void k_gscan(const int* __restrict__ gcnt, int* __restrict__ goff,
                        int NG, int N){
  __shared__ int tmp[1024];
  int t = threadIdx.x;                 // blockDim = 1024
  int v = (t < NG) ? gcnt[t] : 0;
  tmp[t] = v; __syncthreads();
  for (int off = 1; off < 1024; off <<= 1){
    int u = (t >= off) ? tmp[t-off] : 0;
    __syncthreads();
    tmp[t] += u;
    __syncthreads();
  }
  if (t < NG) goff[t] = tmp[t] - v;
  if (t == 0) goff[NG] = N;
}

// ---------------- 2-product f16 MFMA GEMM: C = A·Wh + A·Wl, BK=64 ----------------
// global_load_lds staging (width 16), linear LDS [128][64], XOR chunk swizzle.
__global__ __launch_bounds__(256, 3)
void k_gemm_split(const _Float16* __restrict__ A16, const _Float16* __restrict__ WT,
                  const float* __restrict__ biasL, const float* __restrict__ biasR,
                  _Float16* __restrict__ XL, _Float16* __restrict__ XR,
                  int M, int K, int NwHalf, int gy, int qq, int rr){
  __shared__ _Float16 sA [128*64];
  __shared__ _Float16 sWh[128*64];
  __shared__ _Float16 sWl[128*64];
  const int tid  = threadIdx.x;
  const int lane = tid & 63;
  const int wid  = tid >> 6;
  const int wm   = wid >> 1, wn = wid & 1;

  const int h   = blockIdx.x;
  const int xcd = h & 7, idx = h >> 3;
  const int l   = xcd*qq + (xcd < rr ? xcd : rr) + idx;
  const int bx  = l / gy, by = l - bx*gy;
  const int m0  = bx * 128;
  const int n0  = by * 128;
  const int ldw = 2*K;

  f32x4 acc[4][4];
  #pragma unroll
  for (int i = 0; i < 4; ++i)
    #pragma unroll
    for (int j = 0; j < 4; ++j)
      acc[i][j] = (f32x4){0.f,0.f,0.f,0.f};

  const int l15 = lane & 15;
  const int lhi = lane >> 4;
  const int sub = lane >> 3;   // 0..7
  const int cch = lane & 7;    // chunk 0..7

  const int nc = K/64;
  for (int c = 0; c < nc; ++c){
    const int kA = c*64;
    #pragma unroll
    for (int it = 0; it < 4; ++it){
      int r  = wid*32 + it*8 + sub;
      int cs = cch ^ (r & 7);
      const _Float16* ga = A16 + (size_t)(m0 + r)*K + kA + cs*8;
      const _Float16* gh = WT  + (size_t)(n0 + r)*ldw + kA + cs*8;
      const _Float16* gl = WT  + (size_t)(n0 + r)*ldw + K + kA + cs*8;
      int lb = (wid*32 + it*8)*64;
      __builtin_amdgcn_global_load_lds((gau32*)ga, (lau32*)&sA [lb], 16, 0, 0);
      __builtin_amdgcn_global_load_lds((gau32*)gh, (lau32*)&sWh[lb], 16, 0, 0);
      __builtin_amdgcn_global_load_lds((gau32*)gl, (lau32*)&sWl[lb], 16, 0, 0);
    }
    __syncthreads();
    #pragma unroll
    for (int ks = 0; ks < 2; ++ks){
      const int gc = (ks<<2) | lhi;
      half8 a[4], bh[4], bl[4];
      #pragma unroll
      for (int fm = 0; fm < 4; ++fm){
        int R = wm*64 + fm*16 + l15;
        a[fm] = *(const half8*)&sA[R*64 + (gc ^ (R&7))*8];
      }
      #pragma unroll
      for (int fn = 0; fn < 4; ++fn){
        int R = wn*64 + fn*16 + l15;
        int S = (gc ^ (R&7))*8;
        bh[fn] = *(const half8*)&sWh[R*64 + S];
        bl[fn] = *(const half8*)&sWl[R*64 + S];
      }
      #pragma unroll
      for (int fm = 0; fm < 4; ++fm)
        #pragma unroll
        for (int fn = 0; fn < 4; ++fn)
          acc[fm][fn] = __builtin_amdgcn_mfma_f32_16x16x32_f16(a[fm], bh[fn], acc[fm][fn], 0, 0, 0);
      #pragma unroll
      for (int fm = 0; fm < 4; ++fm)
        #pragma unroll
        for (int fn = 0; fn < 4; ++fn)
          acc[fm][fn] = __builtin_amdgcn_mfma_f32_16x16x32_f16(a[fm], bl[fn], acc[fm][fn], 0, 0, 0);
    }
    __syncthreads();
  }
  const bool isR = (n0 >= NwHalf);
  const float* bias = isR ? biasR : biasL;
  _Float16* Xo = isR ? XR : XL;
  const int nbase = isR ? (n0 - NwHalf) : n0;
  #pragma unroll
  for (int fm = 0; fm < 4; ++fm){
    #pragma unroll
    for (int fn = 0; fn < 4; ++fn){
      int cc = nbase + wn*64 + fn*16 + l15;
      float bv = bias[cc];
      #pragma unroll
      for (int q = 0; q < 4; ++q){
        int row = m0 + wm*64 + fm*16 + lhi*4 + q;
        if (row < M) Xo[(size_t)row*NwHalf + cc] = (_Float16)(acc[fm][fn][q] + bv);
      }
    }
  }
}

// ---------------- GATv2 aggregation (round-11 shape): edge-slot split, update2 ----------------
template<int HC, int C>
__global__ __launch_bounds__(256) void k_gat_agg(const _Float16* __restrict__ xl,
                                                 const _Float16* __restrict__ xr,
                                                 const float* __restrict__ att,
                                                 const float* __restrict__ bias,
                                                 const int* __restrict__ row_start,
                                                 const int* __restrict__ edge_src,
                                                 _Float16* __restrict__ outp,
                                                 int N, int apply_elu){
  constexpr int VEC   = 8;
  constexpr int LPE   = HC/VEC;    // lanes per edge (32 or 16)
  constexpr int EPW   = 64/LPE;    // edge slots per wave (2 or 4)
  constexpr int GROUP = C/VEC;     // lanes per head (8 or 16)
  const float M_INIT = -1.0e30f, T_INACT = -2.0e30f, THR = 11.54f; // ~8 nats

  int wid = (int)(((size_t)blockIdx.x * blockDim.x + threadIdx.x) >> 6);
  int lane = threadIdx.x & 63;
  if (wid >= N) return;
  const int h  = lane / LPE;                       // edge slot
  const int li = lane % LPE;
  const int ch = (li/GROUP)*C + (li%GROUP)*VEC;    // my channel base

  const _Float16 s16 = (_Float16)NEG_SLOPE;
  const half2v slope2 = {s16, s16};

  half2v attv2[4], xrr2[4];
  {
    fvec4 a0 = *(const fvec4*)&att[ch];
    fvec4 a1 = *(const fvec4*)&att[ch+4];
    const float L2E = 1.4426950408889634f;
    attv2[0][0]=(_Float16)(a0[0]*L2E); attv2[0][1]=(_Float16)(a0[1]*L2E);
    attv2[1][0]=(_Float16)(a0[2]*L2E); attv2[1][1]=(_Float16)(a0[3]*L2E);
    attv2[2][0]=(_Float16)(a1[0]*L2E); attv2[2][1]=(_Float16)(a1[1]*L2E);
    attv2[3][0]=(_Float16)(a1[2]*L2E); attv2[3][1]=(_Float16)(a1[3]*L2E);
    half8 hv = *(const half8*)&xr[(unsigned)(wid*HC) + ch];
    #pragma unroll
    for (int p = 0; p < 4; ++p){ xrr2[p][0] = hv[2*p]; xrr2[p][1] = hv[2*p+1]; }
  }

  float acc[VEC];
  #pragma unroll
  for (int q = 0; q < VEC; ++q) acc[q] = 0.f;
  float m = M_INIT, s = 0.f;

  const int e0   = row_start[wid];
  const int ecnt = row_start[wid+1] - e0;
  const _Float16* xlb = xl + ch;

  auto rowload = [&](int sn)->half8 {
    return *(const half8*)(xlb + (unsigned)(sn*HC));
  };
  auto logit1 = [&](half8 x8)->float{
    float t = 0.f;
    #pragma unroll
    for (int p = 0; p < 4; ++p){
      half2v xp; xp[0] = x8[2*p]; xp[1] = x8[2*p+1];
      half2v v  = xp + xrr2[p];
      half2v lv = __builtin_elementwise_max(v, v*slope2);   // leaky relu
      t = __builtin_amdgcn_fdot2(lv, attv2[p], t, false);
    }
    #pragma unroll
    for (int off = GROUP/2; off > 0; off >>= 1)
      t += __shfl_xor(t, off, 64);
    return t;
  };
  auto update2 = [&](float ta, float tb, half8 xa, half8 xb){
    float pm = fmaxf(ta, tb);
    if (__all(pm <= m + THR)){
      float pa = __builtin_amdgcn_exp2f(ta - m);
      float pb = __builtin_amdgcn_exp2f(tb - m);
      s += pa + pb;
      #pragma unroll
      for (int q = 0; q < VEC; ++q)
        acc[q] = fmaf(pa, (float)xa[q], fmaf(pb, (float)xb[q], acc[q]));
    } else {
      float nm = fmaxf(pm, m);
      float wo = __builtin_amdgcn_exp2f(m - nm);
      float pa = __builtin_amdgcn_exp2f(ta - nm);
      float pb = __builtin_amdgcn_exp2f(tb - nm);
      s = fmaf(s, wo, pa + pb);
      m = nm;
      #pragma unroll
      for (int q = 0; q < VEC; ++q)
        acc[q] = fmaf(pa, (float)xa[q], fmaf(pb, (float)xb[q], acc[q]*wo));
    }
  };

  int base = e0 + h;
  const int R = ecnt / (2*EPW);
  for (int r = 0; r < R; ++r, base += 2*EPW){
    int sa = edge_src[base];
    int sb = edge_src[base + EPW];
    half8 xa = rowload(sa);
    half8 xb = rowload(sb);
    float ta = logit1(xa);
    float tb = logit1(xb);
    update2(ta, tb, xa, xb);
  }
  if (2*EPW*R < ecnt){               // predicated tail pair (uniform branch)
    const int last = e0 + ecnt;
    bool a1 = base < last, a2 = base + EPW < last;
    int sa = a1 ? edge_src[base] : 0;
    int sb = a2 ? edge_src[base + EPW] : 0;
    half8 xa = rowload(sa);
    half8 xb = rowload(sb);
    float ta = logit1(xa); ta = a1 ? ta : T_INACT;
    float tb = logit1(xb); tb = a2 ? tb : T_INACT;
    update2(ta, tb, xa, xb);
  }

  // merge edge-slot states (lanes ±LPE hold same channels)
  #pragma unroll
  for (int off = LPE; off < 64; off <<= 1){
    float mo = __shfl_xor(m, off, 64);
    float so = __shfl_xor(s, off, 64);
    float M  = fmaxf(m, mo);
    float w  = __builtin_amdgcn_exp2f(m  - M);
    float wo = __builtin_amdgcn_exp2f(mo - M);
    s = s*w + so*wo;
    #pragma unroll
    for (int q = 0; q < VEC; ++q)
      acc[q] = acc[q]*w + __shfl_xor(acc[q], off, 64)*wo;
    m = M;
  }

  if (h == 0){
    float inv = 1.f / s;
    fvec4 b0 = *(const fvec4*)&bias[ch];
    fvec4 b1 = *(const fvec4*)&bias[ch+4];
    half8 hh;
    #pragma unroll
    for (int q = 0; q < VEC; ++q){
      float o = acc[q]*inv + (q < 4 ? b0[q] : b1[q-4]);
      if (apply_elu) o = (o > 0.f) ? o : (__expf(o) - 1.f);
      hh[q] = (_Float16)o;
    }
    *(half8*)&outp[(unsigned)(wid*HC) + ch] = hh;
  }
}

// ---------------- segmented mean pool: one wave per graph (batch sorted) ----------------
__global__ __launch_bounds__(256) void k_pool_seg(const _Float16* __restrict__ h,
                                                  const int* __restrict__ goff,
                                                  const float* __restrict__ bias,
                                                  float* __restrict__ out, int NG){
  int g = (int)((blockIdx.x*blockDim.x + threadIdx.x) >> 6);
  int lane = threadIdx.x & 63;
  if (g >= NG) return;
  int s0 = goff[g], s1 = goff[g+1];
  float a0 = 0.f, a1 = 0.f;
  for (int n = s0; n < s1; ++n){
    half2v hv = *(const half2v*)&h[(unsigned)(n*128) + lane*2];
    a0 += (float)hv[0];
    a1 += (float)hv[1];
  }
  float inv = 1.f / fmaxf((float)(s1 - s0), 1.f);
  out[(unsigned)(g*128) + lane*2]     = a0*inv + bias[lane*2];
  out[(unsigned)(g*128) + lane*2 + 1] = a1*inv + bias[lane*2 + 1];
}

extern "C" void kernel_launch(void* const* d_in, const int* in_sizes, int n_in,
                              void* d_out, int out_size, void* d_ws, size_t ws_size,
                              hipStream_t stream){
  const float* x    = (const float*)d_in[0];
  const int*   ei   = (const int*)  d_in[1];
  const int*   batch= (const int*)  d_in[2];
  const float* Wl1  = (const float*)d_in[3];
  const float* bl1  = (const float*)d_in[4];
  const float* Wr1  = (const float*)d_in[5];
  const float* br1  = (const float*)d_in[6];
  const float* att1 = (const float*)d_in[7];
  const float* b1   = (const float*)d_in[8];
  const float* Wl2  = (const float*)d_in[9];
  const float* bl2  = (const float*)d_in[10];
  const float* Wr2  = (const float*)d_in[11];
  const float* br2  = (const float*)d_in[12];
  const float* att2 = (const float*)d_in[13];
  const float* b2   = (const float*)d_in[14];
  const float* Wl3  = (const float*)d_in[15];
  const float* bl3  = (const float*)d_in[16];
  const float* Wr3  = (const float*)d_in[17];
  const float* br3  = (const float*)d_in[18];
  const float* att3 = (const float*)d_in[19];
  const float* b3   = (const float*)d_in[20];

  int N  = in_sizes[2];          // 50000
  int E  = in_sizes[1] / 2;      // 800000
  int NG = out_size / 128;       // 1000
  const int* esrc = ei;
  const int* edst = ei + E;
  int Mpad = ((N + 127)/128)*128;

  size_t off = 0;
  char* base = (char*)d_ws;
  auto alloc = [&](size_t bytes)->void*{
    void* p = base + off;
    off += (bytes + 255) & ~(size_t)255;
    return p;
  };
  _Float16* XL  = (_Float16*)alloc((size_t)Mpad*256*sizeof(_Float16));
  _Float16* XR  = (_Float16*)alloc((size_t)Mpad*256*sizeof(_Float16));
  _Float16* H16 = (_Float16*)alloc((size_t)Mpad*256*sizeof(_Float16));
  _Float16* H3  = (_Float16*)alloc((size_t)Mpad*128*sizeof(_Float16));
  _Float16* X16 = (_Float16*)alloc((size_t)Mpad*64*sizeof(_Float16));
  _Float16* WT1 = (_Float16*)alloc((size_t)512*128*sizeof(_Float16));
  _Float16* WT2 = (_Float16*)alloc((size_t)512*512*sizeof(_Float16));
  _Float16* WT3 = (_Float16*)alloc((size_t)256*512*sizeof(_Float16));
  int* row_start = (int*)alloc(((size_t)N+1)*sizeof(int));
  int* edge_src  = (int*)alloc((size_t)(E+N)*sizeof(int));
  size_t cntpad  = ((size_t)N*sizeof(int) + 255) & ~(size_t)255;
  int* cnt       = (int*)alloc((size_t)N*sizeof(int));
  int* gcnt      = (int*)alloc((size_t)NG*sizeof(int));   // adjacent to cnt
  int* bsum      = (int*)alloc(256*sizeof(int));
  int* goff      = (int*)alloc(((size_t)NG+1)*sizeof(int));
  (void)ws_size; (void)n_in;

  int EN = E + N;
  int nb = (N + 255) / 256;
  int nbCH = (EN + 255)/256;          // count+hist blocks
  int nbSW = 229376/256;              // W-split blocks (896)
  int nbCX = (N*8 + 255)/256;         // cvt_x blocks

  // ---- prep ----
  hipMemsetAsync(cnt, 0, cntpad + (size_t)NG*sizeof(int), stream);
  k_prep<<<nbCH + nbSW + nbCX, 256, 0, stream>>>(edst, batch, E, N, cnt, gcnt,
                                                 Wl1, Wr1, Wl2, Wr2, Wl3, Wr3,
                                                 WT1, WT2, WT3, x, X16, nbCH, nbSW);
  k_scan_block<<<nb, 256, 0, stream>>>(cnt, row_start, bsum, N);
  k_scan_tops<<<1, 256, 0, stream>>>(bsum, nb);
  k_scan_add<<<nb, 256, 0, stream>>>(row_start, bsum, N, EN);
  hipMemsetAsync(cnt, 0, (size_t)N*sizeof(int), stream);   // cursor reset
  k_scatter<<<(EN+255)/256, 256, 0, stream>>>(esrc, edst, E, N, row_start, cnt, edge_src);
  k_gscan<<<1, 1024, 0, stream>>>(gcnt, goff, NG, N);

  dim3 blk(256);
  int agg_blocks = (N + 3) / 4;
  int gx = Mpad/128;                  // 391
  int G1 = gx*4;                      // layers 1,2: 512 cols
  int G3 = gx*2;                      // layer 3: 256 cols

  // ---- Layer 1: K=64 -> 4x64 ----
  k_gemm_split<<<G1, blk, 0, stream>>>(X16, WT1, bl1, br1, XL, XR, N, 64, 256, 4, G1/8, G1%8);
  k_gat_agg<256,64><<<agg_blocks, blk, 0, stream>>>(XL, XR, att1, b1, row_start, edge_src, H16, N, 1);

  // ---- Layer 2: K=256 -> 4x64 ----
  k_gemm_split<<<G1, blk, 0, stream>>>(H16, WT2, bl2, br2, XL, XR, N, 256, 256, 4, G1/8, G1%8);
  k_gat_agg<256,64><<<agg_blocks, blk, 0, stream>>>(XL, XR, att2, b2, row_start, edge_src, H16, N, 1);

  // ---- Layer 3: K=256 -> 128, 1 head ----
  k_gemm_split<<<G3, blk, 0, stream>>>(H16, WT3, bl3, br3, XL, XR, N, 256, 128, 2, G3/8, G3%8);
  k_gat_agg<128,128><<<agg_blocks, blk, 0, stream>>>(XL, XR, att3, b3, row_start, edge_src, H3, N, 0);

  // ---- segmented mean pool + bias ----
  k_pool_seg<<<(NG+3)/4, blk, 0, stream>>>(H3, goff, b3, (float*)d_out, NG);
}